// Round 1
// 215.888 us; speedup vs baseline: 1.0156x; 1.0156x over previous
//
#include <hip/hip_runtime.h>
#include <cmath>

// Outputs concatenated flat (all float32):
//   [0)      N*N*3 : dxyz_m
//   [N*N*3)  N*N   : buckets
//   [N*N*4)  N*N   : dscanid
//   [N*N*5)  N*N   : mask

__device__ __forceinline__ float bucket_base(float v) {
    // x = v / RES (RES=0.5 -> exact *2)
    const float x  = v * 2.0f;
    const float xa = fabsf(x);
    if (xa <= 2.0f) {
        // round-half-to-even like jnp.round
        return 8.0f + rintf(x);
    }
    // log path only when needed (xa>2 => x != 0)
    const float lr = logf(fmaxf(xa, 1e-6f) * 0.5f) / 2.0794415416798357f; // /log(8)
    const float sup = fminf(rintf(2.0f - 6.0f * lr), 8.0f);
    return 8.0f + ((x > 0.0f) ? sup : -sup);
}

#define TPB 256   // threads per block (4 waves)
#define JB  1024  // j's per block

__global__ __launch_bounds__(256) void pair_kernel(
    const float* __restrict__ xyz, const int* __restrict__ grid,
    float* __restrict__ out, int N) {
#pragma clang fp contract(off)
    // 12 KB + 20 KB + 12 KB = 44 KB -> 3 blocks/CU
    __shared__ float s_xyz[3 * JB];   // packed AoS, j-local [0,1024)
    __shared__ int   s_grid[5 * JB];
    __shared__ float s_st[3 * JB];    // per-wave dxyz transpose staging

    const int tid = threadIdx.x;
    const int i   = blockIdx.y;
    const int J0  = blockIdx.x * JB;

    // ---- Phase 1: cooperative staging; every load/store lane-contiguous ----
    {
        const float4* gx = reinterpret_cast<const float4*>(xyz + (size_t)3 * J0);
        float4* sx = reinterpret_cast<float4*>(s_xyz);
#pragma unroll
        for (int p = 0; p < 3; ++p) sx[TPB * p + tid] = gx[TPB * p + tid];
        const int4* gg = reinterpret_cast<const int4*>(grid + (size_t)5 * J0);
        int4* sg = reinterpret_cast<int4*>(s_grid);
#pragma unroll
        for (int p = 0; p < 5; ++p) sg[TPB * p + tid] = gg[TPB * p + tid];
    }

    // i-side (wave-uniform -> scalar loads)
    const float xi = xyz[3 * i + 0];
    const float yi = xyz[3 * i + 1];
    const float zi = xyz[3 * i + 2];
    const int bat_i = grid[5 * i + 0];
    const int blk_i = grid[5 * i + 1];
    const int c0i = grid[5 * i + 2];
    const int c1i = grid[5 * i + 3];
    const int c2i = grid[5 * i + 4];
    const int xci = (int)ceilf(xi / 3.0f);
    const int yci = (int)ceilf(yi / 3.0f);
    const int scan_i = blk_i >> 1;

    __syncthreads();

    const int w   = tid >> 6;   // wave id within block
    const int l   = tid & 63;   // lane
    const int jw0 = 256 * w;    // wave's j-local base; wave owns [jw0, jw0+256)

    // ---- Phase 2: compute; thread handles j-local = jw0 + 64k + l ----
    float dxm[4], dym[4], dzm[4];
    int   jblkA[4];
    bool  mk[4];
    bool  any = false;
#pragma unroll
    for (int k = 0; k < 4; ++k) {
        const int jl = jw0 + 64 * k + l;
        const float jx = s_xyz[3 * jl + 0];
        const float jy = s_xyz[3 * jl + 1];
        const float jz = s_xyz[3 * jl + 2];
        const int jbat = s_grid[5 * jl + 0];
        const int jblk = s_grid[5 * jl + 1];
        const int jc0  = s_grid[5 * jl + 2];
        const int jc1  = s_grid[5 * jl + 3];
        const int jc2  = s_grid[5 * jl + 4];

        const float dx = xi - jx;
        const float dy = yi - jy;
        const float dz = zi - jz;
        const bool batch_eq = (bat_i == jbat);
        const bool block_le = (blk_i <= jblk);
        const int  cadj = max(max(abs(c0i - jc0), abs(c1i - jc1)),
                              abs(c2i - jc2));
        const bool forcekeep = (cadj <= 1) && (blk_i == jblk);
        const int xcj = (int)ceilf(jx / 3.0f);
        const int ycj = (int)ceilf(jy / 3.0f);
        const bool keep_coarse = max(abs(xci - xcj), abs(yci - ycj)) <= 1;
        const float d2 = dx * dx + dy * dy + dz * dz; // contract(off): matches ref
        const bool keepr = (d2 <= 9.0f);
        const bool m = batch_eq && block_le &&
                       (forcekeep || keep_coarse) && (forcekeep || keepr);
        mk[k] = m;
        any |= m;
        jblkA[k] = jblk;
        dxm[k] = m ? dx : 0.0f;
        dym[k] = m ? dy : 0.0f;
        dzm[k] = m ? dz : 0.0f;
    }

    const size_t NN      = (size_t)N * (size_t)N;
    const size_t rowbase = (size_t)i * (size_t)N + (size_t)J0;
    float* __restrict__ obkt = out + NN * 3 + rowbase;
    float* __restrict__ odsc = out + NN * 4 + rowbase;
    float* __restrict__ omsk = out + NN * 5 + rowbase;
    // wave's dxyz span: floats [3*(rowbase+jw0), +768) ; 16B-aligned
    float4* __restrict__ od4 =
        reinterpret_cast<float4*>(out + 3 * (rowbase + (size_t)jw0));

    // ---- Wave-uniform fast path: all-zero wave -> coalesced zero stores ----
    if (__ballot(any ? 1 : 0) == 0ULL) {
        const float4 z4 = make_float4(0.0f, 0.0f, 0.0f, 0.0f);
#pragma unroll
        for (int p = 0; p < 3; ++p) od4[64 * p + l] = z4;
#pragma unroll
        for (int k = 0; k < 4; ++k) {
            const int jl = jw0 + 64 * k + l;
            obkt[jl] = 0.0f;
            odsc[jl] = 0.0f;
            omsk[jl] = 0.0f;
        }
        return;
    }

    // ---- Slow path: buckets + dword stores + wave-local dxyz transpose ----
#pragma unroll
    for (int k = 0; k < 4; ++k) {
        const int jl = jw0 + 64 * k + l;
        float b = 0.0f, d = 0.0f, mvf = 0.0f;
        if (mk[k]) {
            const float b0 = bucket_base(dxm[k]);
            const float b1 = bucket_base(dym[k]);
            const float b2 = bucket_base(dzm[k]);
            const float bsum = (289.0f * b0 + 17.0f * b1) + b2; // exact small ints
            b   = (float)(int)bsum;
            d   = (float)((jblkA[k] >> 1) - scan_i);
            mvf = 1.0f;
        }
        // lane-contiguous dword stores (full lines, 4 lines/instr)
        obkt[jl] = b;
        odsc[jl] = d;
        omsk[jl] = mvf;
        // stage dxyz into wave-private LDS region (stride-12B writes, ~free)
        s_st[3 * jl + 0] = dxm[k];
        s_st[3 * jl + 1] = dym[k];
        s_st[3 * jl + 2] = dzm[k];
    }

    // Wave-local transpose readback: sequential float4 -> 3 fully-coalesced
    // 1024B store instructions. Same-wave DS ordering; no barrier needed.
    const float4* st4 = reinterpret_cast<const float4*>(s_st + 3 * jw0);
#pragma unroll
    for (int p = 0; p < 3; ++p) od4[64 * p + l] = st4[64 * p + l];
}

extern "C" void kernel_launch(void* const* d_in, const int* in_sizes, int n_in,
                              void* d_out, int out_size, void* d_ws, size_t ws_size,
                              hipStream_t stream) {
    const float* xyz  = (const float*)d_in[0];
    const int*   grid = (const int*)d_in[1];
    float*       out  = (float*)d_out;
    const int N = in_sizes[0] / 3; // xyz is (N,3); N=3072, divisible by JB

    dim3 gdim(N / JB, N, 1);       // (3, 3072)
    pair_kernel<<<gdim, dim3(TPB, 1, 1), 0, stream>>>(xyz, grid, out, N);
}